// Round 1
// baseline (1460.318 us; speedup 1.0000x reference)
//
#include <hip/hip_runtime.h>

#define NN 100000
#define NE 1600000
#define DI 128
#define DH 128
#define DO 64

// ---- degree ----------------------------------------------------------------
__global__ void k_deg_init(float* deg) {
    int i = blockIdx.x * blockDim.x + threadIdx.x;
    if (i < NN) deg[i] = 1.0f;  // self-loop
}

__global__ void k_deg_count(const int* __restrict__ dst, float* deg) {
    int e = blockIdx.x * blockDim.x + threadIdx.x;
    if (e < NE) atomicAdd(&deg[dst[e]], 1.0f);
}

__global__ void k_deg_inv(float* deg) {  // in place: deg -> rsqrt(deg)
    int i = blockIdx.x * blockDim.x + threadIdx.x;
    if (i < NN) deg[i] = rsqrtf(deg[i]);
}

// ---- row GEMM: one block computes one output row ---------------------------
// out[row*M + j] = sum_k A[row*K + k] * W[k*M + j]
template <int K, int M>
__global__ void k_gemm_rows(const float* __restrict__ A,
                            const float* __restrict__ W,
                            float* __restrict__ out) {
    __shared__ float a[K];
    int row = blockIdx.x;
    for (int k = threadIdx.x; k < K; k += blockDim.x) a[k] = A[row * K + k];
    __syncthreads();
    int j = threadIdx.x;  // blockDim.x == M
    float acc = 0.f;
#pragma unroll 8
    for (int k = 0; k < K; ++k) acc = fmaf(a[k], W[k * M + j], acc);
    out[row * M + j] = acc;
}

// ---- self-loop init: out[i,f] = h[i,f]*inv[i]^2 (+ bias) -------------------
template <int D, bool BIAS>
__global__ void k_self_init(const float* __restrict__ h,
                            const float* __restrict__ inv,
                            const float* __restrict__ bias,
                            float* __restrict__ out) {
    int t = blockIdx.x * blockDim.x + threadIdx.x;
    if (t >= NN * D) return;
    int i = t / D;
    int f = t & (D - 1);
    float c = inv[i] * inv[i];
    float v = h[t] * c;
    if (BIAS) v += bias[f];
    out[t] = v;
}

// ---- per-edge scatter: out[dst,f] += h[src,f]*inv[src]*inv[dst] ------------
template <int D>
__global__ void k_scatter(const int* __restrict__ src,
                          const int* __restrict__ dst,
                          const float* __restrict__ h,
                          const float* __restrict__ inv,
                          float* __restrict__ out) {
    long long t = (long long)blockIdx.x * blockDim.x + threadIdx.x;
    if (t >= (long long)NE * D) return;
    int e = (int)(t / D);
    int f = (int)(t & (D - 1));
    int s = src[e];
    int d = dst[e];
    float c = inv[s] * inv[d];
    atomicAdd(&out[(long long)d * D + f], h[(long long)s * D + f] * c);
}

// ---- bias + relu in place ---------------------------------------------------
__global__ void k_bias_relu(float* __restrict__ h, const float* __restrict__ b) {
    int t = blockIdx.x * blockDim.x + threadIdx.x;
    if (t >= NN * DH) return;
    int f = t & (DH - 1);
    h[t] = fmaxf(h[t] + b[f], 0.f);
}

extern "C" void kernel_launch(void* const* d_in, const int* in_sizes, int n_in,
                              void* d_out, int out_size, void* d_ws, size_t ws_size,
                              hipStream_t stream) {
    const float* x  = (const float*)d_in[0];
    const int* ei   = (const int*)d_in[1];
    const int* src  = ei;        // edge_index[0]
    const int* dst  = ei + NE;   // edge_index[1]
    const float* W1 = (const float*)d_in[2];
    const float* b1 = (const float*)d_in[3];
    const float* W2 = (const float*)d_in[4];
    const float* b2 = (const float*)d_in[5];
    float* out = (float*)d_out;

    float* ws  = (float*)d_ws;
    float* inv = ws;                 // N  (deg, then rsqrt in place)
    float* h   = inv + NN;           // N*128  (x @ W1)
    float* agg = h + (size_t)NN * DH;  // N*128  (aggregated, then h1 in place)
    float* h2  = agg + (size_t)NN * DH; // N*64  (h1 @ W2)

    // degrees -> inv sqrt
    k_deg_init<<<(NN + 255) / 256, 256, 0, stream>>>(inv);
    k_deg_count<<<(NE + 255) / 256, 256, 0, stream>>>(dst, inv);
    k_deg_inv<<<(NN + 255) / 256, 256, 0, stream>>>(inv);

    // layer 1
    k_gemm_rows<DI, DH><<<NN, DH, 0, stream>>>(x, W1, h);
    k_self_init<DH, false><<<(NN * DH + 255) / 256, 256, 0, stream>>>(h, inv, nullptr, agg);
    {
        long long tot = (long long)NE * DH;
        int blocks = (int)((tot + 255) / 256);
        k_scatter<DH><<<blocks, 256, 0, stream>>>(src, dst, h, inv, agg);
    }
    k_bias_relu<<<(NN * DH + 255) / 256, 256, 0, stream>>>(agg, b1);

    // layer 2
    k_gemm_rows<DH, DO><<<NN, DO, 0, stream>>>(agg, W2, h2);
    k_self_init<DO, true><<<(NN * DO + 255) / 256, 256, 0, stream>>>(h2, inv, b2, out);
    {
        long long tot = (long long)NE * DO;
        int blocks = (int)((tot + 255) / 256);
        k_scatter<DO><<<blocks, 256, 0, stream>>>(src, dst, h2, inv, out);
    }
}

// Round 2
// 721.350 us; speedup vs baseline: 2.0244x; 2.0244x over previous
//
#include <hip/hip_runtime.h>

#define NN 100000
#define NE 1600000
#define DI 128
#define DH 128
#define DO 64

// ---------------- CSR build ----------------
__global__ void k_zero(int* p, int n) {
    int i = blockIdx.x * blockDim.x + threadIdx.x;
    if (i < n) p[i] = 0;
}

__global__ void k_hist(const int* __restrict__ dst, int* __restrict__ cnt) {
    int e = blockIdx.x * blockDim.x + threadIdx.x;
    if (e < NE) atomicAdd(&cnt[dst[e]], 1);
}

// single-block exclusive scan of cnt[0..NN) -> off[0..NN], off[NN]=NE
__global__ void k_scan(const int* __restrict__ cnt, int* __restrict__ off) {
    __shared__ int part[1024];
    const int chunk = (NN + 1023) / 1024;  // 98
    int tid = threadIdx.x;
    int start = tid * chunk;
    int endi = min(start + chunk, NN);
    int s = 0;
    for (int i = start; i < endi; ++i) s += cnt[i];
    part[tid] = s;
    __syncthreads();
    for (int d = 1; d < 1024; d <<= 1) {
        int v = part[tid];
        int add = (tid >= d) ? part[tid - d] : 0;
        __syncthreads();
        part[tid] = v + add;
        __syncthreads();
    }
    int base = (tid == 0) ? 0 : part[tid - 1];
    for (int i = start; i < endi; ++i) { off[i] = base; base += cnt[i]; }
    if (tid == 1023) off[NN] = NE;
}

__global__ void k_copy(const int* __restrict__ a, int* __restrict__ b, int n) {
    int i = blockIdx.x * blockDim.x + threadIdx.x;
    if (i < n) b[i] = a[i];
}

__global__ void k_deg_inv(const int* __restrict__ cnt, float* __restrict__ inv) {
    int i = blockIdx.x * blockDim.x + threadIdx.x;
    if (i < NN) inv[i] = rsqrtf((float)cnt[i] + 1.0f);  // +1 self-loop
}

__global__ void k_fill(const int* __restrict__ src, const int* __restrict__ dst,
                       int* __restrict__ cursor, int* __restrict__ csr_src) {
    int e = blockIdx.x * blockDim.x + threadIdx.x;
    if (e < NE) {
        int d = dst[e];
        int p = atomicAdd(&cursor[d], 1);
        csr_src[p] = src[e];
    }
}

// ---------------- row GEMM: 8 rows per block ----------------
// out[row*M + j] = sum_k A[row*K + k] * W[k*M + j]; blockDim.x == M
template <int K, int M, int ROWS>
__global__ void k_gemm_rows(const float* __restrict__ A,
                            const float* __restrict__ W,
                            float* __restrict__ out) {
    __shared__ float a[ROWS][K];
    int row0 = blockIdx.x * ROWS;
    for (int t = threadIdx.x; t < ROWS * K; t += blockDim.x) {
        int r = t / K, k = t % K;
        a[r][k] = A[(size_t)(row0 + r) * K + k];
    }
    __syncthreads();
    int j = threadIdx.x;
    float acc[ROWS];
#pragma unroll
    for (int r = 0; r < ROWS; ++r) acc[r] = 0.f;
    for (int k = 0; k < K; ++k) {
        float wv = W[k * M + j];
#pragma unroll
        for (int r = 0; r < ROWS; ++r) acc[r] = fmaf(a[r][k], wv, acc[r]);
    }
#pragma unroll
    for (int r = 0; r < ROWS; ++r) out[(size_t)(row0 + r) * M + j] = acc[r];
}

// ---------------- gather aggregation: one wave per node ----------------
// out[d] = inv[d] * sum_{e in row d} inv[src] * h[src] + inv[d]^2 * h[d] + bias
template <int D, bool RELU>
__global__ void k_aggregate(const int* __restrict__ off,
                            const int* __restrict__ csr_src,
                            const float* __restrict__ h,
                            const float* __restrict__ inv,
                            const float* __restrict__ bias,
                            float* __restrict__ out) {
    constexpr int V = D / 64;  // floats per lane (2 for D=128, 1 for D=64)
    int wid = threadIdx.x >> 6;
    int lane = threadIdx.x & 63;
    int node = blockIdx.x * (blockDim.x >> 6) + wid;
    if (node >= NN) return;

    int beg = off[node];
    int end = off[node + 1];
    float acc[V];
#pragma unroll
    for (int v = 0; v < V; ++v) acc[v] = 0.f;

    int e = beg;
    for (; e + 1 < end; e += 2) {
        int s0 = csr_src[e];
        int s1 = csr_src[e + 1];
        float c0 = inv[s0];
        float c1 = inv[s1];
        const float* p0 = h + (size_t)s0 * D + lane * V;
        const float* p1 = h + (size_t)s1 * D + lane * V;
        if (V == 2) {
            float2 h0 = *(const float2*)p0;
            float2 h1 = *(const float2*)p1;
            acc[0] = fmaf(h0.x, c0, acc[0]);
            acc[1] = fmaf(h0.y, c0, acc[1]);
            acc[0] = fmaf(h1.x, c1, acc[0]);
            acc[1] = fmaf(h1.y, c1, acc[1]);
        } else {
            acc[0] = fmaf(p0[0], c0, acc[0]);
            acc[0] = fmaf(p1[0], c1, acc[0]);
        }
    }
    if (e < end) {
        int s0 = csr_src[e];
        float c0 = inv[s0];
        const float* p0 = h + (size_t)s0 * D + lane * V;
#pragma unroll
        for (int v = 0; v < V; ++v) acc[v] = fmaf(p0[v], c0, acc[v]);
    }

    float invd = inv[node];
    const float* ps = h + (size_t)node * D + lane * V;
    float res[V];
#pragma unroll
    for (int v = 0; v < V; ++v) {
        res[v] = invd * acc[v] + invd * invd * ps[v] + bias[lane * V + v];
        if (RELU) res[v] = fmaxf(res[v], 0.f);
    }
    float* po = out + (size_t)node * D + lane * V;
    if (V == 2) {
        *(float2*)po = make_float2(res[0], res[1]);
    } else {
        po[0] = res[0];
    }
}

extern "C" void kernel_launch(void* const* d_in, const int* in_sizes, int n_in,
                              void* d_out, int out_size, void* d_ws, size_t ws_size,
                              hipStream_t stream) {
    const float* x  = (const float*)d_in[0];
    const int* ei   = (const int*)d_in[1];
    const int* src  = ei;        // edge_index[0]
    const int* dst  = ei + NE;   // edge_index[1]
    const float* W1 = (const float*)d_in[2];
    const float* b1 = (const float*)d_in[3];
    const float* W2 = (const float*)d_in[4];
    const float* b2 = (const float*)d_in[5];
    float* out = (float*)d_out;

    // workspace layout (element offsets, all 16B-aligned)
    char* ws = (char*)d_ws;
    int*   cnt     = (int*)(ws);                      // N ints        [0, 100000)
    int*   off     = cnt + 100000;                    // N+1 ints, pad to 100004
    int*   cursor  = off + 100004;                    // N ints
    float* inv     = (float*)(cursor + 100000);       // N floats
    int*   csr_src = (int*)(inv + 100004);            // E ints
    float* h       = (float*)(csr_src + 1600000);     // N*128 floats
    float* agg     = h + (size_t)NN * DH;             // N*128 floats
    float* h2      = h;                               // alias: h free after layer-1 agg

    // CSR + normalization
    k_zero<<<(NN + 255) / 256, 256, 0, stream>>>(cnt, NN);
    k_hist<<<(NE + 255) / 256, 256, 0, stream>>>(dst, cnt);
    k_scan<<<1, 1024, 0, stream>>>(cnt, off);
    k_deg_inv<<<(NN + 255) / 256, 256, 0, stream>>>(cnt, inv);
    k_copy<<<(NN + 255) / 256, 256, 0, stream>>>(off, cursor, NN);
    k_fill<<<(NE + 255) / 256, 256, 0, stream>>>(src, dst, cursor, csr_src);

    // layer 1: h = x @ W1 ; agg = relu(A_hat h + b1)
    k_gemm_rows<DI, DH, 8><<<NN / 8, DH, 0, stream>>>(x, W1, h);
    k_aggregate<DH, true><<<NN / 4, 256, 0, stream>>>(off, csr_src, h, inv, b1, agg);

    // layer 2: h2 = agg @ W2 ; out = A_hat h2 + b2
    k_gemm_rows<DH, DO, 8><<<NN / 8, DO, 0, stream>>>(agg, W2, h2);
    k_aggregate<DO, false><<<NN / 4, 256, 0, stream>>>(off, csr_src, h2, inv, b2, out);
}

// Round 3
// 699.187 us; speedup vs baseline: 2.0886x; 1.0317x over previous
//
#include <hip/hip_runtime.h>

#define NN 100000
#define NE 1600000
#define DI 128
#define DH 128
#define DO 64

typedef unsigned int uint;
typedef unsigned short ushort;

// ---- bf16 helpers (manual, RTNE) ----
__device__ __forceinline__ float bf_lo(uint u) { return __uint_as_float(u << 16); }
__device__ __forceinline__ float bf_hi(uint u) { return __uint_as_float(u & 0xffff0000u); }
__device__ __forceinline__ ushort f2bf(float f) {
    uint u = __float_as_uint(f);
    uint r = u + 0x7fffu + ((u >> 16) & 1u);
    return (ushort)(r >> 16);
}

// ---------------- CSR build ----------------
__global__ void k_zero(int* p, int n) {
    int i = blockIdx.x * blockDim.x + threadIdx.x;
    if (i < n) p[i] = 0;
}

__global__ void k_hist(const int* __restrict__ dst, int* __restrict__ cnt) {
    int e = blockIdx.x * blockDim.x + threadIdx.x;
    if (e < NE) atomicAdd(&cnt[dst[e]], 1);
}

// single-block exclusive scan of cnt[0..NN) -> off[0..NN], off[NN]=NE
__global__ void k_scan(const int* __restrict__ cnt, int* __restrict__ off) {
    __shared__ int part[1024];
    const int chunk = (NN + 1023) / 1024;  // 98
    int tid = threadIdx.x;
    int start = tid * chunk;
    int endi = min(start + chunk, NN);
    int s = 0;
    for (int i = start; i < endi; ++i) s += cnt[i];
    part[tid] = s;
    __syncthreads();
    for (int d = 1; d < 1024; d <<= 1) {
        int v = part[tid];
        int add = (tid >= d) ? part[tid - d] : 0;
        __syncthreads();
        part[tid] = v + add;
        __syncthreads();
    }
    int base = (tid == 0) ? 0 : part[tid - 1];
    for (int i = start; i < endi; ++i) { off[i] = base; base += cnt[i]; }
    if (tid == 1023) off[NN] = NE;
}

// inv[i] = rsqrt(deg_i + 1) ; cursor[i] = off[i]
__global__ void k_deg_inv_copy(const int* __restrict__ cnt, const int* __restrict__ off,
                               float* __restrict__ inv, int* __restrict__ cursor) {
    int i = blockIdx.x * blockDim.x + threadIdx.x;
    if (i < NN) {
        inv[i] = rsqrtf((float)cnt[i] + 1.0f);
        cursor[i] = off[i];
    }
}

__global__ void k_fill(const int* __restrict__ src, const int* __restrict__ dst,
                       int* __restrict__ cursor, int* __restrict__ csr_src) {
    int e = blockIdx.x * blockDim.x + threadIdx.x;
    if (e < NE) {
        int d = dst[e];
        int p = atomicAdd(&cursor[d], 1);
        csr_src[p] = src[e];
    }
}

// ---------------- row GEMM: scalar-pipe A, bf16 out ----------------
// out[row*M + j] = bf16( sum_k A[row*K + k] * W[k*M + j] ); blockDim.x == M
template <int K, int M, int ROWS>
__global__ void k_gemm_bf16(const float* __restrict__ A,
                            const float* __restrict__ W,
                            ushort* __restrict__ out) {
    int row0 = blockIdx.x * ROWS;
    int j = threadIdx.x;
    float acc[ROWS];
#pragma unroll
    for (int r = 0; r < ROWS; ++r) acc[r] = 0.f;
#pragma unroll 4
    for (int k = 0; k < K; ++k) {
        float wv = W[k * M + j];
#pragma unroll
        for (int r = 0; r < ROWS; ++r)
            acc[r] = fmaf(A[(size_t)(row0 + r) * K + k], wv, acc[r]);
    }
#pragma unroll
    for (int r = 0; r < ROWS; ++r) out[(size_t)(row0 + r) * M + j] = f2bf(acc[r]);
}

// ---------------- gather aggregation, D=128, bf16 table ----------------
// out[d] = inv[d] * sum inv[s]*tab[s] + inv[d]^2 * tab[d] + bias  (fp32 out)
template <bool RELU>
__global__ void k_agg128(const int* __restrict__ off, const int* __restrict__ csr,
                         const ushort* __restrict__ tab,  // bf16 [NN][128]
                         const float* __restrict__ inv,
                         const float* __restrict__ bias,
                         float* __restrict__ out) {
    int wid = threadIdx.x >> 6, lane = threadIdx.x & 63;
    int node = blockIdx.x * (blockDim.x >> 6) + wid;
    if (node >= NN) return;
    int beg = off[node], end = off[node + 1];
    const uint* t32 = (const uint*)tab;  // [NN][64] packed bf16 pairs
    float a0 = 0.f, a1 = 0.f;
    int e = beg;
    for (; e + 3 < end; e += 4) {
        int s0 = csr[e], s1 = csr[e + 1], s2 = csr[e + 2], s3 = csr[e + 3];
        float c0 = inv[s0], c1 = inv[s1], c2 = inv[s2], c3 = inv[s3];
        uint u0 = t32[(size_t)s0 * 64 + lane];
        uint u1 = t32[(size_t)s1 * 64 + lane];
        uint u2 = t32[(size_t)s2 * 64 + lane];
        uint u3 = t32[(size_t)s3 * 64 + lane];
        a0 = fmaf(bf_lo(u0), c0, a0); a1 = fmaf(bf_hi(u0), c0, a1);
        a0 = fmaf(bf_lo(u1), c1, a0); a1 = fmaf(bf_hi(u1), c1, a1);
        a0 = fmaf(bf_lo(u2), c2, a0); a1 = fmaf(bf_hi(u2), c2, a1);
        a0 = fmaf(bf_lo(u3), c3, a0); a1 = fmaf(bf_hi(u3), c3, a1);
    }
    for (; e < end; ++e) {
        int s = csr[e];
        float c = inv[s];
        uint u = t32[(size_t)s * 64 + lane];
        a0 = fmaf(bf_lo(u), c, a0); a1 = fmaf(bf_hi(u), c, a1);
    }
    float invd = inv[node];
    uint us = t32[(size_t)node * 64 + lane];
    float2 b = *(const float2*)(bias + lane * 2);
    float r0 = invd * a0 + invd * invd * bf_lo(us) + b.x;
    float r1 = invd * a1 + invd * invd * bf_hi(us) + b.y;
    if (RELU) { r0 = fmaxf(r0, 0.f); r1 = fmaxf(r1, 0.f); }
    *(float2*)(out + (size_t)node * 128 + lane * 2) = make_float2(r0, r1);
}

// ---------------- gather aggregation, D=64, bf16 table ----------------
template <bool RELU>
__global__ void k_agg64(const int* __restrict__ off, const int* __restrict__ csr,
                        const ushort* __restrict__ tab,  // bf16 [NN][64]
                        const float* __restrict__ inv,
                        const float* __restrict__ bias,
                        float* __restrict__ out) {
    int wid = threadIdx.x >> 6, lane = threadIdx.x & 63;
    int node = blockIdx.x * (blockDim.x >> 6) + wid;
    if (node >= NN) return;
    int beg = off[node], end = off[node + 1];
    float a0 = 0.f;
    int e = beg;
    for (; e + 3 < end; e += 4) {
        int s0 = csr[e], s1 = csr[e + 1], s2 = csr[e + 2], s3 = csr[e + 3];
        float c0 = inv[s0], c1 = inv[s1], c2 = inv[s2], c3 = inv[s3];
        float h0 = __uint_as_float((uint)tab[(size_t)s0 * 64 + lane] << 16);
        float h1 = __uint_as_float((uint)tab[(size_t)s1 * 64 + lane] << 16);
        float h2 = __uint_as_float((uint)tab[(size_t)s2 * 64 + lane] << 16);
        float h3 = __uint_as_float((uint)tab[(size_t)s3 * 64 + lane] << 16);
        a0 = fmaf(h0, c0, a0);
        a0 = fmaf(h1, c1, a0);
        a0 = fmaf(h2, c2, a0);
        a0 = fmaf(h3, c3, a0);
    }
    for (; e < end; ++e) {
        int s = csr[e];
        float c = inv[s];
        float h0 = __uint_as_float((uint)tab[(size_t)s * 64 + lane] << 16);
        a0 = fmaf(h0, c, a0);
    }
    float invd = inv[node];
    float hs = __uint_as_float((uint)tab[(size_t)node * 64 + lane] << 16);
    float r0 = invd * a0 + invd * invd * hs + bias[lane];
    if (RELU) r0 = fmaxf(r0, 0.f);
    out[(size_t)node * 64 + lane] = r0;
}

extern "C" void kernel_launch(void* const* d_in, const int* in_sizes, int n_in,
                              void* d_out, int out_size, void* d_ws, size_t ws_size,
                              hipStream_t stream) {
    const float* x  = (const float*)d_in[0];
    const int* ei   = (const int*)d_in[1];
    const int* src  = ei;        // edge_index[0]
    const int* dst  = ei + NE;   // edge_index[1]
    const float* W1 = (const float*)d_in[2];
    const float* b1 = (const float*)d_in[3];
    const float* W2 = (const float*)d_in[4];
    const float* b2 = (const float*)d_in[5];
    float* out = (float*)d_out;

    // workspace layout
    char* ws = (char*)d_ws;
    int*    cnt     = (int*)ws;                        // 100000 ints
    int*    off     = cnt + 100000;                    // 100004 ints
    int*    cursor  = off + 100004;                    // 100000 ints
    float*  inv     = (float*)(cursor + 100000);       // 100004 floats
    int*    csr_src = (int*)(inv + 100004);            // 1600000 ints
    ushort* h       = (ushort*)(csr_src + 1600000);    // NN*128 bf16
    float*  agg     = (float*)(h + (size_t)NN * DH);   // NN*128 fp32
    ushort* h2      = (ushort*)(agg + (size_t)NN * DH);// NN*64 bf16

    // CSR + normalization
    k_zero<<<(NN + 255) / 256, 256, 0, stream>>>(cnt, NN);
    k_hist<<<(NE + 255) / 256, 256, 0, stream>>>(dst, cnt);
    k_scan<<<1, 1024, 0, stream>>>(cnt, off);
    k_deg_inv_copy<<<(NN + 255) / 256, 256, 0, stream>>>(cnt, off, inv, cursor);
    k_fill<<<(NE + 255) / 256, 256, 0, stream>>>(src, dst, cursor, csr_src);

    // layer 1: h = bf16(x @ W1) ; agg = relu(A_hat h + b1)  (fp32)
    k_gemm_bf16<DI, DH, 16><<<NN / 16, DH, 0, stream>>>(x, W1, h);
    k_agg128<true><<<NN / 4, 256, 0, stream>>>(off, csr_src, h, inv, b1, agg);

    // layer 2: h2 = bf16(agg @ W2) ; out = A_hat h2 + b2  (fp32)
    k_gemm_bf16<DH, DO, 16><<<NN / 16, DO, 0, stream>>>(agg, W2, h2);
    k_agg64<false><<<NN / 4, 256, 0, stream>>>(off, csr_src, h2, inv, b2, out);
}

// Round 4
// 550.985 us; speedup vs baseline: 2.6504x; 1.2690x over previous
//
#include <hip/hip_runtime.h>

#define NN 100000
#define NE 1600000
#define DI 128
#define DH 128
#define DO 64

typedef unsigned int uint;
typedef unsigned short ushort;
typedef __bf16 bf16x8 __attribute__((ext_vector_type(8)));
typedef float f32x4 __attribute__((ext_vector_type(4)));

// ---- bf16 helpers (manual, RTNE) ----
__device__ __forceinline__ float bf_lo(uint u) { return __uint_as_float(u << 16); }
__device__ __forceinline__ float bf_hi(uint u) { return __uint_as_float(u & 0xffff0000u); }
__device__ __forceinline__ ushort f2bf(float f) {
    uint u = __float_as_uint(f);
    uint r = u + 0x7fffu + ((u >> 16) & 1u);
    return (ushort)(r >> 16);
}

// ---------------- CSR build ----------------
__global__ void k_zero(int* p, int n) {
    int i = blockIdx.x * blockDim.x + threadIdx.x;
    if (i < n) p[i] = 0;
}

__global__ void k_hist(const int* __restrict__ dst, int* __restrict__ cnt) {
    int e = blockIdx.x * blockDim.x + threadIdx.x;
    if (e < NE) atomicAdd(&cnt[dst[e]], 1);
}

// single-block exclusive scan of cnt[0..NN) -> off[0..NN], off[NN]=NE
__global__ void k_scan(const int* __restrict__ cnt, int* __restrict__ off) {
    __shared__ int part[1024];
    const int chunk = (NN + 1023) / 1024;  // 98
    int tid = threadIdx.x;
    int start = tid * chunk;
    int endi = min(start + chunk, NN);
    int s = 0;
    for (int i = start; i < endi; ++i) s += cnt[i];
    part[tid] = s;
    __syncthreads();
    for (int d = 1; d < 1024; d <<= 1) {
        int v = part[tid];
        int add = (tid >= d) ? part[tid - d] : 0;
        __syncthreads();
        part[tid] = v + add;
        __syncthreads();
    }
    int base = (tid == 0) ? 0 : part[tid - 1];
    for (int i = start; i < endi; ++i) { off[i] = base; base += cnt[i]; }
    if (tid == 1023) off[NN] = NE;
}

__global__ void k_deg_inv_copy(const int* __restrict__ cnt, const int* __restrict__ off,
                               float* __restrict__ inv, int* __restrict__ cursor) {
    int i = blockIdx.x * blockDim.x + threadIdx.x;
    if (i < NN) {
        inv[i] = rsqrtf((float)cnt[i] + 1.0f);
        cursor[i] = off[i];
    }
}

__global__ void k_fill(const int* __restrict__ src, const int* __restrict__ dst,
                       int* __restrict__ cursor, int* __restrict__ csr_src) {
    int e = blockIdx.x * blockDim.x + threadIdx.x;
    if (e < NE) {
        int d = dst[e];
        int p = atomicAdd(&cursor[d], 1);
        csr_src[p] = src[e];
    }
}

// ---------------- W transpose to bf16: Wt[c][k] = bf16(W[k][c]) ----------------
__global__ void k_wt(const float* __restrict__ W, ushort* __restrict__ Wt, int K, int N) {
    int t = blockIdx.x * blockDim.x + threadIdx.x;
    if (t < K * N) {
        int c = t / K, k = t % K;
        Wt[t] = f2bf(W[k * N + c]);
    }
}

// ---------------- MFMA GEMM: one wave = 32 rows x N cols, K=128 ----------------
// A: fp32 or bf16 [NN][128]; Wt: bf16 [N][128] (col-major W); out: bf16 [NN][N]
template <int N, bool ABF16>
__global__ __launch_bounds__(256) void k_gemm_mfma(const void* __restrict__ Ap,
                                                   const ushort* __restrict__ Wt,
                                                   ushort* __restrict__ out) {
    int wid = threadIdx.x >> 6;
    int lane = threadIdx.x & 63;
    int r0 = (blockIdx.x * 4 + wid) * 32;
    if (r0 >= NN) return;
    int rlo = lane & 15, khi = lane >> 4;  // khi in 0..3

    constexpr int CT = N / 16;  // 8 (N=128) or 4 (N=64)
    f32x4 acc[2][CT] = {};

#pragma unroll
    for (int ks = 0; ks < 4; ++ks) {
        bf16x8 bf[CT];
#pragma unroll
        for (int ct = 0; ct < CT; ++ct)
            bf[ct] = *(const bf16x8*)(Wt + (ct * 16 + rlo) * 128 + ks * 32 + khi * 8);
#pragma unroll
        for (int rt = 0; rt < 2; ++rt) {
            int row = r0 + rt * 16 + rlo;
            bf16x8 af;
            if (ABF16) {
                af = *(const bf16x8*)((const ushort*)Ap + (size_t)row * 128 + ks * 32 + khi * 8);
            } else {
                const float* pa = (const float*)Ap + (size_t)row * 128 + ks * 32 + khi * 8;
                float4 f0 = *(const float4*)pa;
                float4 f1 = *(const float4*)(pa + 4);
                af[0] = (__bf16)f0.x; af[1] = (__bf16)f0.y;
                af[2] = (__bf16)f0.z; af[3] = (__bf16)f0.w;
                af[4] = (__bf16)f1.x; af[5] = (__bf16)f1.y;
                af[6] = (__bf16)f1.z; af[7] = (__bf16)f1.w;
            }
#pragma unroll
            for (int ct = 0; ct < CT; ++ct)
                acc[rt][ct] = __builtin_amdgcn_mfma_f32_16x16x32_bf16(af, bf[ct], acc[rt][ct], 0, 0, 0);
        }
    }
    // D: col = lane&15, row = 4*(lane>>4) + b
#pragma unroll
    for (int rt = 0; rt < 2; ++rt) {
        int rowb = r0 + rt * 16 + 4 * khi;
#pragma unroll
        for (int ct = 0; ct < CT; ++ct)
#pragma unroll
            for (int b = 0; b < 4; ++b)
                out[(size_t)(rowb + b) * N + ct * 16 + rlo] = f2bf(acc[rt][ct][b]);
    }
}

// ---------------- gather aggregation, D=128, bf16 table -> bf16 out ----------------
template <bool RELU>
__global__ void k_agg128(const int* __restrict__ off, const int* __restrict__ csr,
                         const ushort* __restrict__ tab, const float* __restrict__ inv,
                         const float* __restrict__ bias, ushort* __restrict__ outb) {
    int wid = threadIdx.x >> 6, lane = threadIdx.x & 63;
    int node = blockIdx.x * (blockDim.x >> 6) + wid;
    if (node >= NN) return;
    int beg = off[node], end = off[node + 1];
    const uint* t32 = (const uint*)tab;  // [NN][64] packed bf16 pairs
    float a0 = 0.f, a1 = 0.f;
    int e = beg;
    for (; e + 3 < end; e += 4) {
        int s0 = csr[e], s1 = csr[e + 1], s2 = csr[e + 2], s3 = csr[e + 3];
        float c0 = inv[s0], c1 = inv[s1], c2 = inv[s2], c3 = inv[s3];
        uint u0 = t32[(size_t)s0 * 64 + lane];
        uint u1 = t32[(size_t)s1 * 64 + lane];
        uint u2 = t32[(size_t)s2 * 64 + lane];
        uint u3 = t32[(size_t)s3 * 64 + lane];
        a0 = fmaf(bf_lo(u0), c0, a0); a1 = fmaf(bf_hi(u0), c0, a1);
        a0 = fmaf(bf_lo(u1), c1, a0); a1 = fmaf(bf_hi(u1), c1, a1);
        a0 = fmaf(bf_lo(u2), c2, a0); a1 = fmaf(bf_hi(u2), c2, a1);
        a0 = fmaf(bf_lo(u3), c3, a0); a1 = fmaf(bf_hi(u3), c3, a1);
    }
    for (; e < end; ++e) {
        int s = csr[e];
        float c = inv[s];
        uint u = t32[(size_t)s * 64 + lane];
        a0 = fmaf(bf_lo(u), c, a0); a1 = fmaf(bf_hi(u), c, a1);
    }
    float invd = inv[node];
    uint us = t32[(size_t)node * 64 + lane];
    float2 b = *(const float2*)(bias + lane * 2);
    float r0 = invd * a0 + invd * invd * bf_lo(us) + b.x;
    float r1 = invd * a1 + invd * invd * bf_hi(us) + b.y;
    if (RELU) { r0 = fmaxf(r0, 0.f); r1 = fmaxf(r1, 0.f); }
    uint packed = (uint)f2bf(r0) | ((uint)f2bf(r1) << 16);
    *(uint*)(outb + (size_t)node * 128 + lane * 2) = packed;
}

// ---------------- gather aggregation, D=64, bf16 table -> fp32 out ----------------
__global__ void k_agg64(const int* __restrict__ off, const int* __restrict__ csr,
                        const ushort* __restrict__ tab, const float* __restrict__ inv,
                        const float* __restrict__ bias, float* __restrict__ out) {
    int wid = threadIdx.x >> 6, lane = threadIdx.x & 63;
    int node = blockIdx.x * (blockDim.x >> 6) + wid;
    if (node >= NN) return;
    int beg = off[node], end = off[node + 1];
    float a0 = 0.f;
    int e = beg;
    for (; e + 3 < end; e += 4) {
        int s0 = csr[e], s1 = csr[e + 1], s2 = csr[e + 2], s3 = csr[e + 3];
        float c0 = inv[s0], c1 = inv[s1], c2 = inv[s2], c3 = inv[s3];
        float h0 = __uint_as_float((uint)tab[(size_t)s0 * 64 + lane] << 16);
        float h1 = __uint_as_float((uint)tab[(size_t)s1 * 64 + lane] << 16);
        float h2 = __uint_as_float((uint)tab[(size_t)s2 * 64 + lane] << 16);
        float h3 = __uint_as_float((uint)tab[(size_t)s3 * 64 + lane] << 16);
        a0 = fmaf(h0, c0, a0);
        a0 = fmaf(h1, c1, a0);
        a0 = fmaf(h2, c2, a0);
        a0 = fmaf(h3, c3, a0);
    }
    for (; e < end; ++e) {
        int s = csr[e];
        float c = inv[s];
        a0 = fmaf(__uint_as_float((uint)tab[(size_t)s * 64 + lane] << 16), c, a0);
    }
    float invd = inv[node];
    float hs = __uint_as_float((uint)tab[(size_t)node * 64 + lane] << 16);
    float r0 = invd * a0 + invd * invd * hs + bias[lane];
    out[(size_t)node * 64 + lane] = r0;
}

extern "C" void kernel_launch(void* const* d_in, const int* in_sizes, int n_in,
                              void* d_out, int out_size, void* d_ws, size_t ws_size,
                              hipStream_t stream) {
    const float* x  = (const float*)d_in[0];
    const int* ei   = (const int*)d_in[1];
    const int* src  = ei;        // edge_index[0]
    const int* dst  = ei + NE;   // edge_index[1]
    const float* W1 = (const float*)d_in[2];
    const float* b1 = (const float*)d_in[3];
    const float* W2 = (const float*)d_in[4];
    const float* b2 = (const float*)d_in[5];
    float* out = (float*)d_out;

    // workspace layout (16B alignment maintained)
    char* ws = (char*)d_ws;
    int*    cnt     = (int*)ws;                          // 100000 ints
    int*    off     = cnt + 100000;                      // 100004 ints
    int*    cursor  = off + 100004;                      // 100000 ints
    float*  inv     = (float*)(cursor + 100000);         // 100004 floats
    int*    csr_src = (int*)(inv + 100004);              // 1600000 ints
    ushort* w1t     = (ushort*)(csr_src + 1600000);      // 128*128 bf16
    ushort* w2t     = w1t + 128 * 128;                   // 64*128 bf16
    ushort* h       = w2t + 64 * 128;                    // NN*128 bf16
    ushort* hagg    = h + (size_t)NN * DH;               // NN*128 bf16
    ushort* h2      = hagg + (size_t)NN * DH;            // NN*64 bf16

    // CSR + normalization + weight prep
    k_zero<<<(NN + 255) / 256, 256, 0, stream>>>(cnt, NN);
    k_hist<<<(NE + 255) / 256, 256, 0, stream>>>(dst, cnt);
    k_scan<<<1, 1024, 0, stream>>>(cnt, off);
    k_deg_inv_copy<<<(NN + 255) / 256, 256, 0, stream>>>(cnt, off, inv, cursor);
    k_fill<<<(NE + 255) / 256, 256, 0, stream>>>(src, dst, cursor, csr_src);
    k_wt<<<64, 256, 0, stream>>>(W1, w1t, 128, 128);
    k_wt<<<32, 256, 0, stream>>>(W2, w2t, 128, 64);

    // layer 1: h = bf16(x @ W1) ; hagg = bf16(relu(A_hat h + b1))
    k_gemm_mfma<DH, false><<<(NN + 127) / 128, 256, 0, stream>>>(x, w1t, h);
    k_agg128<true><<<NN / 4, 256, 0, stream>>>(off, csr_src, h, inv, b1, hagg);

    // layer 2: h2 = bf16(hagg @ W2) ; out = A_hat h2 + b2  (fp32)
    k_gemm_mfma<DO, true><<<(NN + 127) / 128, 256, 0, stream>>>(hagg, w2t, h2);
    k_agg64<<<NN / 4, 256, 0, stream>>>(off, csr_src, h2, inv, b2, out);
}

// Round 5
// 402.205 us; speedup vs baseline: 3.6308x; 1.3699x over previous
//
#include <hip/hip_runtime.h>

#define NN 100000
#define NE 1600000
#define DI 128
#define DH 128
#define DO 64
#define NB ((NN + 255) / 256)  // 391 scan blocks

typedef unsigned int uint;
typedef unsigned short ushort;
typedef __bf16 bf16x8 __attribute__((ext_vector_type(8)));
typedef float f32x4 __attribute__((ext_vector_type(4)));

// ---- bf16 helpers (manual, RTNE) ----
__device__ __forceinline__ float bf_lo(uint u) { return __uint_as_float(u << 16); }
__device__ __forceinline__ float bf_hi(uint u) { return __uint_as_float(u & 0xffff0000u); }
__device__ __forceinline__ ushort f2bf(float f) {
    uint u = __float_as_uint(f);
    uint r = u + 0x7fffu + ((u >> 16) & 1u);
    return (ushort)(r >> 16);
}

// ---------------- CSR build ----------------
__global__ void k_zero(int* p, int n) {
    int i = blockIdx.x * blockDim.x + threadIdx.x;
    if (i < n) p[i] = 0;
}

__global__ void k_hist(const int* __restrict__ dst, int* __restrict__ cnt) {
    int e = blockIdx.x * blockDim.x + threadIdx.x;
    if (e < NE) atomicAdd(&cnt[dst[e]], 1);
}

// phase 1: per-block sum of 256 counts
__global__ void k_bsum(const int* __restrict__ cnt, int* __restrict__ bsum) {
    int i = blockIdx.x * 256 + threadIdx.x;
    int v = (i < NN) ? cnt[i] : 0;
#pragma unroll
    for (int m = 1; m < 64; m <<= 1) v += __shfl_xor(v, m);
    __shared__ int wsum[4];
    if ((threadIdx.x & 63) == 0) wsum[threadIdx.x >> 6] = v;
    __syncthreads();
    if (threadIdx.x == 0) bsum[blockIdx.x] = wsum[0] + wsum[1] + wsum[2] + wsum[3];
}

// phase 2: single block scans NB block sums -> exclusive base per block
__global__ void k_scan_bsum(const int* __restrict__ bsum, int* __restrict__ bbase) {
    __shared__ int s[512];
    int t = threadIdx.x;
    int v = (t < NB) ? bsum[t] : 0;
    s[t] = v;
    __syncthreads();
    for (int d = 1; d < 512; d <<= 1) {
        int add = (t >= d) ? s[t - d] : 0;
        __syncthreads();
        s[t] += add;
        __syncthreads();
    }
    if (t < NB) bbase[t] = s[t] - v;  // exclusive
}

// phase 3: intra-block scan + base; also emit inv and cursor
__global__ void k_scan_final(const int* __restrict__ cnt, const int* __restrict__ bbase,
                             int* __restrict__ off, int* __restrict__ cursor,
                             float* __restrict__ inv) {
    int i = blockIdx.x * 256 + threadIdx.x;
    int t = threadIdx.x;
    int v = (i < NN) ? cnt[i] : 0;
    __shared__ int s[256];
    s[t] = v;
    __syncthreads();
    for (int d = 1; d < 256; d <<= 1) {
        int add = (t >= d) ? s[t - d] : 0;
        __syncthreads();
        s[t] += add;
        __syncthreads();
    }
    if (i < NN) {
        int o = bbase[blockIdx.x] + s[t] - v;  // exclusive scan
        off[i] = o;
        cursor[i] = o;
        inv[i] = rsqrtf((float)v + 1.0f);
        if (i == NN - 1) off[NN] = NE;
    }
}

__global__ void k_fill(const int* __restrict__ src, const int* __restrict__ dst,
                       int* __restrict__ cursor, int* __restrict__ csr_src) {
    int e = blockIdx.x * blockDim.x + threadIdx.x;
    if (e < NE) {
        int d = dst[e];
        int p = atomicAdd(&cursor[d], 1);
        csr_src[p] = src[e];
    }
}

// ---------------- W transpose to bf16: Wt[c][k] = bf16(W[k][c]) ----------------
__global__ void k_wt(const float* __restrict__ W, ushort* __restrict__ Wt, int K, int N) {
    int t = blockIdx.x * blockDim.x + threadIdx.x;
    if (t < K * N) {
        int c = t / K, k = t % K;
        Wt[t] = f2bf(W[k * N + c]);
    }
}

// ---------------- MFMA GEMM: one wave = 32 rows x N cols, K=128 ----------------
template <int N, bool ABF16>
__global__ __launch_bounds__(256) void k_gemm_mfma(const void* __restrict__ Ap,
                                                   const ushort* __restrict__ Wt,
                                                   ushort* __restrict__ out) {
    int wid = threadIdx.x >> 6;
    int lane = threadIdx.x & 63;
    int r0 = (blockIdx.x * 4 + wid) * 32;
    if (r0 >= NN) return;
    int rlo = lane & 15, khi = lane >> 4;  // khi in 0..3

    constexpr int CT = N / 16;  // 8 (N=128) or 4 (N=64)
    f32x4 acc[2][CT] = {};

#pragma unroll
    for (int ks = 0; ks < 4; ++ks) {
        bf16x8 bf[CT];
#pragma unroll
        for (int ct = 0; ct < CT; ++ct)
            bf[ct] = *(const bf16x8*)(Wt + (ct * 16 + rlo) * 128 + ks * 32 + khi * 8);
#pragma unroll
        for (int rt = 0; rt < 2; ++rt) {
            int row = r0 + rt * 16 + rlo;
            bf16x8 af;
            if (ABF16) {
                af = *(const bf16x8*)((const ushort*)Ap + (size_t)row * 128 + ks * 32 + khi * 8);
            } else {
                const float* pa = (const float*)Ap + (size_t)row * 128 + ks * 32 + khi * 8;
                float4 f0 = *(const float4*)pa;
                float4 f1 = *(const float4*)(pa + 4);
                af[0] = (__bf16)f0.x; af[1] = (__bf16)f0.y;
                af[2] = (__bf16)f0.z; af[3] = (__bf16)f0.w;
                af[4] = (__bf16)f1.x; af[5] = (__bf16)f1.y;
                af[6] = (__bf16)f1.z; af[7] = (__bf16)f1.w;
            }
#pragma unroll
            for (int ct = 0; ct < CT; ++ct)
                acc[rt][ct] = __builtin_amdgcn_mfma_f32_16x16x32_bf16(af, bf[ct], acc[rt][ct], 0, 0, 0);
        }
    }
#pragma unroll
    for (int rt = 0; rt < 2; ++rt) {
        int rowb = r0 + rt * 16 + 4 * khi;
#pragma unroll
        for (int ct = 0; ct < CT; ++ct)
#pragma unroll
            for (int b = 0; b < 4; ++b)
                out[(size_t)(rowb + b) * N + ct * 16 + rlo] = f2bf(acc[rt][ct][b]);
    }
}

// ---------------- gather aggregation, D=128, bf16 table -> bf16 out ----------------
template <bool RELU>
__global__ void k_agg128(const int* __restrict__ off, const int* __restrict__ csr,
                         const ushort* __restrict__ tab, const float* __restrict__ inv,
                         const float* __restrict__ bias, ushort* __restrict__ outb) {
    int wid = threadIdx.x >> 6, lane = threadIdx.x & 63;
    int node = blockIdx.x * (blockDim.x >> 6) + wid;
    if (node >= NN) return;
    int beg = off[node], end = off[node + 1];
    const uint* t32 = (const uint*)tab;  // [NN][64] packed bf16 pairs
    float a0 = 0.f, a1 = 0.f;
    int e = beg;
    for (; e + 3 < end; e += 4) {
        int s0 = csr[e], s1 = csr[e + 1], s2 = csr[e + 2], s3 = csr[e + 3];
        float c0 = inv[s0], c1 = inv[s1], c2 = inv[s2], c3 = inv[s3];
        uint u0 = t32[(size_t)s0 * 64 + lane];
        uint u1 = t32[(size_t)s1 * 64 + lane];
        uint u2 = t32[(size_t)s2 * 64 + lane];
        uint u3 = t32[(size_t)s3 * 64 + lane];
        a0 = fmaf(bf_lo(u0), c0, a0); a1 = fmaf(bf_hi(u0), c0, a1);
        a0 = fmaf(bf_lo(u1), c1, a0); a1 = fmaf(bf_hi(u1), c1, a1);
        a0 = fmaf(bf_lo(u2), c2, a0); a1 = fmaf(bf_hi(u2), c2, a1);
        a0 = fmaf(bf_lo(u3), c3, a0); a1 = fmaf(bf_hi(u3), c3, a1);
    }
    for (; e < end; ++e) {
        int s = csr[e];
        float c = inv[s];
        uint u = t32[(size_t)s * 64 + lane];
        a0 = fmaf(bf_lo(u), c, a0); a1 = fmaf(bf_hi(u), c, a1);
    }
    float invd = inv[node];
    uint us = t32[(size_t)node * 64 + lane];
    float2 b = *(const float2*)(bias + lane * 2);
    float r0 = invd * a0 + invd * invd * bf_lo(us) + b.x;
    float r1 = invd * a1 + invd * invd * bf_hi(us) + b.y;
    if (RELU) { r0 = fmaxf(r0, 0.f); r1 = fmaxf(r1, 0.f); }
    uint packed = (uint)f2bf(r0) | ((uint)f2bf(r1) << 16);
    *(uint*)(outb + (size_t)node * 128 + lane * 2) = packed;
}

// ---------------- gather aggregation, D=64, bf16 table -> fp32 out ----------------
__global__ void k_agg64(const int* __restrict__ off, const int* __restrict__ csr,
                        const ushort* __restrict__ tab, const float* __restrict__ inv,
                        const float* __restrict__ bias, float* __restrict__ out) {
    int wid = threadIdx.x >> 6, lane = threadIdx.x & 63;
    int node = blockIdx.x * (blockDim.x >> 6) + wid;
    if (node >= NN) return;
    int beg = off[node], end = off[node + 1];
    float a0 = 0.f;
    int e = beg;
    for (; e + 3 < end; e += 4) {
        int s0 = csr[e], s1 = csr[e + 1], s2 = csr[e + 2], s3 = csr[e + 3];
        float c0 = inv[s0], c1 = inv[s1], c2 = inv[s2], c3 = inv[s3];
        float h0 = __uint_as_float((uint)tab[(size_t)s0 * 64 + lane] << 16);
        float h1 = __uint_as_float((uint)tab[(size_t)s1 * 64 + lane] << 16);
        float h2 = __uint_as_float((uint)tab[(size_t)s2 * 64 + lane] << 16);
        float h3 = __uint_as_float((uint)tab[(size_t)s3 * 64 + lane] << 16);
        a0 = fmaf(h0, c0, a0);
        a0 = fmaf(h1, c1, a0);
        a0 = fmaf(h2, c2, a0);
        a0 = fmaf(h3, c3, a0);
    }
    for (; e < end; ++e) {
        int s = csr[e];
        float c = inv[s];
        a0 = fmaf(__uint_as_float((uint)tab[(size_t)s * 64 + lane] << 16), c, a0);
    }
    float invd = inv[node];
    float hs = __uint_as_float((uint)tab[(size_t)node * 64 + lane] << 16);
    float r0 = invd * a0 + invd * invd * hs + bias[lane];
    out[(size_t)node * 64 + lane] = r0;
}

extern "C" void kernel_launch(void* const* d_in, const int* in_sizes, int n_in,
                              void* d_out, int out_size, void* d_ws, size_t ws_size,
                              hipStream_t stream) {
    const float* x  = (const float*)d_in[0];
    const int* ei   = (const int*)d_in[1];
    const int* src  = ei;        // edge_index[0]
    const int* dst  = ei + NE;   // edge_index[1]
    const float* W1 = (const float*)d_in[2];
    const float* b1 = (const float*)d_in[3];
    const float* W2 = (const float*)d_in[4];
    const float* b2 = (const float*)d_in[5];
    float* out = (float*)d_out;

    // workspace layout (16B alignment maintained)
    char* ws = (char*)d_ws;
    int*    cnt     = (int*)ws;                          // 100000 ints
    int*    off     = cnt + 100000;                      // 100004 ints
    int*    cursor  = off + 100004;                      // 100000 ints
    float*  inv     = (float*)(cursor + 100000);         // 100004 floats
    int*    bsum    = (int*)(inv + 100004);              // 512 ints
    int*    bbase   = bsum + 512;                        // 512 ints
    int*    csr_src = bbase + 512;                       // 1600000 ints
    ushort* w1t     = (ushort*)(csr_src + 1600000);      // 128*128 bf16
    ushort* w2t     = w1t + 128 * 128;                   // 64*128 bf16
    ushort* h       = w2t + 64 * 128;                    // NN*128 bf16
    ushort* hagg    = h + (size_t)NN * DH;               // NN*128 bf16
    ushort* h2      = hagg + (size_t)NN * DH;            // NN*64 bf16

    // CSR + normalization + weight prep
    k_zero<<<(NN + 255) / 256, 256, 0, stream>>>(cnt, NN);
    k_hist<<<(NE + 255) / 256, 256, 0, stream>>>(dst, cnt);
    k_bsum<<<NB, 256, 0, stream>>>(cnt, bsum);
    k_scan_bsum<<<1, 512, 0, stream>>>(bsum, bbase);
    k_scan_final<<<NB, 256, 0, stream>>>(cnt, bbase, off, cursor, inv);
    k_fill<<<(NE + 255) / 256, 256, 0, stream>>>(src, dst, cursor, csr_src);
    k_wt<<<64, 256, 0, stream>>>(W1, w1t, 128, 128);
    k_wt<<<32, 256, 0, stream>>>(W2, w2t, 128, 64);

    // layer 1: h = bf16(x @ W1) ; hagg = bf16(relu(A_hat h + b1))
    k_gemm_mfma<DH, false><<<(NN + 127) / 128, 256, 0, stream>>>(x, w1t, h);
    k_agg128<true><<<NN / 4, 256, 0, stream>>>(off, csr_src, h, inv, b1, hagg);

    // layer 2: h2 = bf16(hagg @ W2) ; out = A_hat h2 + b2  (fp32)
    k_gemm_mfma<DO, true><<<(NN + 127) / 128, 256, 0, stream>>>(hagg, w2t, h2);
    k_agg64<<<NN / 4, 256, 0, stream>>>(off, csr_src, h2, inv, b2, out);
}

// Round 6
// 346.873 us; speedup vs baseline: 4.2099x; 1.1595x over previous
//
#include <hip/hip_runtime.h>

#define NN 100000
#define NE 1600000
#define DI 128
#define DH 128
#define DO 64
#define BNODES 256
#define NBK ((NN + BNODES - 1) / BNODES)  // 391 buckets
#define PAD 16                             // one counter per 64B line

typedef unsigned int uint;
typedef unsigned short ushort;
typedef __bf16 bf16x8 __attribute__((ext_vector_type(8)));
typedef float f32x4 __attribute__((ext_vector_type(4)));

// ---- bf16 helpers (manual, RTNE) ----
__device__ __forceinline__ float bf_lo(uint u) { return __uint_as_float(u << 16); }
__device__ __forceinline__ float bf_hi(uint u) { return __uint_as_float(u & 0xffff0000u); }
__device__ __forceinline__ ushort f2bf(float f) {
    uint u = __float_as_uint(f);
    uint r = u + 0x7fffu + ((u >> 16) & 1u);
    return (ushort)(r >> 16);
}

__global__ void k_zero(int* p, int n) {
    int i = blockIdx.x * blockDim.x + threadIdx.x;
    if (i < n) p[i] = 0;
}

// ---- Pass A: bucket histogram via LDS privatization ----
__global__ void k_bhist(const int* __restrict__ dst, int* __restrict__ bcnt) {
    __shared__ int h[NBK + 1];
    for (int i = threadIdx.x; i < NBK; i += 256) h[i] = 0;
    __syncthreads();
    for (int e = blockIdx.x * 256 + threadIdx.x; e < NE; e += gridDim.x * 256)
        atomicAdd(&h[dst[e] >> 8], 1);
    __syncthreads();
    for (int i = threadIdx.x; i < NBK; i += 256)
        if (h[i]) atomicAdd(&bcnt[i * PAD], h[i]);
}

// ---- Pass B: scan bucket counts -> bbase[0..NBK], bcur (padded) ----
__global__ void k_bscan(const int* __restrict__ bcnt, int* __restrict__ bbase,
                        int* __restrict__ bcur) {
    __shared__ int s[512];
    int t = threadIdx.x;
    int v = (t < NBK) ? bcnt[t * PAD] : 0;
    s[t] = v;
    __syncthreads();
    for (int d = 1; d < 512; d <<= 1) {
        int a = (t >= d) ? s[t - d] : 0;
        __syncthreads();
        s[t] += a;
        __syncthreads();
    }
    if (t < NBK) {
        int b = s[t] - v;  // exclusive
        bbase[t] = b;
        bcur[t * PAD] = b;
    }
    if (t == NBK - 1) bbase[NBK] = s[t];  // == NE
}

// ---- Pass C: scatter packed (src,dst) into bucket regions ----
__global__ void k_bscatter(const int* __restrict__ src, const int* __restrict__ dst,
                           int* __restrict__ bcur, uint2* __restrict__ ebuf) {
    int e = blockIdx.x * 256 + threadIdx.x;
    if (e < NE) {
        int d = dst[e];
        int p = atomicAdd(&bcur[(d >> 8) * PAD], 1);
        ebuf[p] = make_uint2((uint)src[e], (uint)d);
    }
}

// ---- Pass D: per-bucket node hist + scan + fill; emits off, inv, csr ----
__global__ __launch_bounds__(256) void k_bfill(const uint2* __restrict__ ebuf,
                                               const int* __restrict__ bbase,
                                               int* __restrict__ off,
                                               float* __restrict__ inv,
                                               int* __restrict__ csr_src) {
    __shared__ int cnt[BNODES];
    __shared__ int s[BNODES];
    __shared__ int cur[BNODES];
    int b = blockIdx.x;
    int t = threadIdx.x;
    int ebeg = bbase[b];
    int eend = bbase[b + 1];
    cnt[t] = 0;
    __syncthreads();
    for (int e = ebeg + t; e < eend; e += 256)
        atomicAdd(&cnt[ebuf[e].y & 255], 1);
    __syncthreads();
    int v = cnt[t];
    s[t] = v;
    __syncthreads();
    for (int d = 1; d < 256; d <<= 1) {
        int a = (t >= d) ? s[t - d] : 0;
        __syncthreads();
        s[t] += a;
        __syncthreads();
    }
    int excl = s[t] - v;
    int node = b * BNODES + t;
    if (node < NN) {
        off[node] = ebeg + excl;
        inv[node] = rsqrtf((float)v + 1.0f);
    }
    cur[t] = ebeg + excl;
    __syncthreads();
    for (int e = ebeg + t; e < eend; e += 256) {
        uint2 ed = ebuf[e];
        int p = atomicAdd(&cur[ed.y & 255], 1);
        csr_src[p] = (int)ed.x;
    }
    if (b == 0 && t == 0) off[NN] = NE;
}

// ---------------- W transpose to bf16: Wt[c][k] = bf16(W[k][c]) ----------------
__global__ void k_wt(const float* __restrict__ W, ushort* __restrict__ Wt, int K, int N) {
    int t = blockIdx.x * blockDim.x + threadIdx.x;
    if (t < K * N) {
        int c = t / K, k = t % K;
        Wt[t] = f2bf(W[k * N + c]);
    }
}

// ---------------- MFMA GEMM: one wave = 32 rows x N cols, K=128 ----------------
template <int N, bool ABF16>
__global__ __launch_bounds__(256) void k_gemm_mfma(const void* __restrict__ Ap,
                                                   const ushort* __restrict__ Wt,
                                                   ushort* __restrict__ out) {
    int wid = threadIdx.x >> 6;
    int lane = threadIdx.x & 63;
    int r0 = (blockIdx.x * 4 + wid) * 32;
    if (r0 >= NN) return;
    int rlo = lane & 15, khi = lane >> 4;  // khi in 0..3

    constexpr int CT = N / 16;  // 8 (N=128) or 4 (N=64)
    f32x4 acc[2][CT] = {};

#pragma unroll
    for (int ks = 0; ks < 4; ++ks) {
        bf16x8 bf[CT];
#pragma unroll
        for (int ct = 0; ct < CT; ++ct)
            bf[ct] = *(const bf16x8*)(Wt + (ct * 16 + rlo) * 128 + ks * 32 + khi * 8);
#pragma unroll
        for (int rt = 0; rt < 2; ++rt) {
            int row = r0 + rt * 16 + rlo;
            bf16x8 af;
            if (ABF16) {
                af = *(const bf16x8*)((const ushort*)Ap + (size_t)row * 128 + ks * 32 + khi * 8);
            } else {
                const float* pa = (const float*)Ap + (size_t)row * 128 + ks * 32 + khi * 8;
                float4 f0 = *(const float4*)pa;
                float4 f1 = *(const float4*)(pa + 4);
                af[0] = (__bf16)f0.x; af[1] = (__bf16)f0.y;
                af[2] = (__bf16)f0.z; af[3] = (__bf16)f0.w;
                af[4] = (__bf16)f1.x; af[5] = (__bf16)f1.y;
                af[6] = (__bf16)f1.z; af[7] = (__bf16)f1.w;
            }
#pragma unroll
            for (int ct = 0; ct < CT; ++ct)
                acc[rt][ct] = __builtin_amdgcn_mfma_f32_16x16x32_bf16(af, bf[ct], acc[rt][ct], 0, 0, 0);
        }
    }
#pragma unroll
    for (int rt = 0; rt < 2; ++rt) {
        int rowb = r0 + rt * 16 + 4 * khi;
#pragma unroll
        for (int ct = 0; ct < CT; ++ct)
#pragma unroll
            for (int b = 0; b < 4; ++b)
                out[(size_t)(rowb + b) * N + ct * 16 + rlo] = f2bf(acc[rt][ct][b]);
    }
}

// ---------------- gather aggregation, D=128, bf16 table -> bf16 out ----------------
template <bool RELU>
__global__ void k_agg128(const int* __restrict__ off, const int* __restrict__ csr,
                         const ushort* __restrict__ tab, const float* __restrict__ inv,
                         const float* __restrict__ bias, ushort* __restrict__ outb) {
    int wid = threadIdx.x >> 6, lane = threadIdx.x & 63;
    int node = blockIdx.x * (blockDim.x >> 6) + wid;
    if (node >= NN) return;
    int beg = off[node], end = off[node + 1];
    const uint* t32 = (const uint*)tab;  // [NN][64] packed bf16 pairs
    float a0 = 0.f, a1 = 0.f;
    int e = beg;
    for (; e + 3 < end; e += 4) {
        int s0 = csr[e], s1 = csr[e + 1], s2 = csr[e + 2], s3 = csr[e + 3];
        float c0 = inv[s0], c1 = inv[s1], c2 = inv[s2], c3 = inv[s3];
        uint u0 = t32[(size_t)s0 * 64 + lane];
        uint u1 = t32[(size_t)s1 * 64 + lane];
        uint u2 = t32[(size_t)s2 * 64 + lane];
        uint u3 = t32[(size_t)s3 * 64 + lane];
        a0 = fmaf(bf_lo(u0), c0, a0); a1 = fmaf(bf_hi(u0), c0, a1);
        a0 = fmaf(bf_lo(u1), c1, a0); a1 = fmaf(bf_hi(u1), c1, a1);
        a0 = fmaf(bf_lo(u2), c2, a0); a1 = fmaf(bf_hi(u2), c2, a1);
        a0 = fmaf(bf_lo(u3), c3, a0); a1 = fmaf(bf_hi(u3), c3, a1);
    }
    for (; e < end; ++e) {
        int s = csr[e];
        float c = inv[s];
        uint u = t32[(size_t)s * 64 + lane];
        a0 = fmaf(bf_lo(u), c, a0); a1 = fmaf(bf_hi(u), c, a1);
    }
    float invd = inv[node];
    uint us = t32[(size_t)node * 64 + lane];
    float2 b = *(const float2*)(bias + lane * 2);
    float r0 = invd * a0 + invd * invd * bf_lo(us) + b.x;
    float r1 = invd * a1 + invd * invd * bf_hi(us) + b.y;
    if (RELU) { r0 = fmaxf(r0, 0.f); r1 = fmaxf(r1, 0.f); }
    uint packed = (uint)f2bf(r0) | ((uint)f2bf(r1) << 16);
    *(uint*)(outb + (size_t)node * 128 + lane * 2) = packed;
}

// ---------------- gather aggregation, D=64, bf16 table -> fp32 out ----------------
__global__ void k_agg64(const int* __restrict__ off, const int* __restrict__ csr,
                        const ushort* __restrict__ tab, const float* __restrict__ inv,
                        const float* __restrict__ bias, float* __restrict__ out) {
    int wid = threadIdx.x >> 6, lane = threadIdx.x & 63;
    int node = blockIdx.x * (blockDim.x >> 6) + wid;
    if (node >= NN) return;
    int beg = off[node], end = off[node + 1];
    float a0 = 0.f;
    int e = beg;
    for (; e + 3 < end; e += 4) {
        int s0 = csr[e], s1 = csr[e + 1], s2 = csr[e + 2], s3 = csr[e + 3];
        float c0 = inv[s0], c1 = inv[s1], c2 = inv[s2], c3 = inv[s3];
        float h0 = __uint_as_float((uint)tab[(size_t)s0 * 64 + lane] << 16);
        float h1 = __uint_as_float((uint)tab[(size_t)s1 * 64 + lane] << 16);
        float h2 = __uint_as_float((uint)tab[(size_t)s2 * 64 + lane] << 16);
        float h3 = __uint_as_float((uint)tab[(size_t)s3 * 64 + lane] << 16);
        a0 = fmaf(h0, c0, a0);
        a0 = fmaf(h1, c1, a0);
        a0 = fmaf(h2, c2, a0);
        a0 = fmaf(h3, c3, a0);
    }
    for (; e < end; ++e) {
        int s = csr[e];
        float c = inv[s];
        a0 = fmaf(__uint_as_float((uint)tab[(size_t)s * 64 + lane] << 16), c, a0);
    }
    float invd = inv[node];
    float hs = __uint_as_float((uint)tab[(size_t)node * 64 + lane] << 16);
    float r0 = invd * a0 + invd * invd * hs + bias[lane];
    out[(size_t)node * 64 + lane] = r0;
}

extern "C" void kernel_launch(void* const* d_in, const int* in_sizes, int n_in,
                              void* d_out, int out_size, void* d_ws, size_t ws_size,
                              hipStream_t stream) {
    const float* x  = (const float*)d_in[0];
    const int* ei   = (const int*)d_in[1];
    const int* src  = ei;        // edge_index[0]
    const int* dst  = ei + NE;   // edge_index[1]
    const float* W1 = (const float*)d_in[2];
    const float* b1 = (const float*)d_in[3];
    const float* W2 = (const float*)d_in[4];
    const float* b2 = (const float*)d_in[5];
    float* out = (float*)d_out;

    // workspace layout (16B alignment maintained)
    int*    off     = (int*)d_ws;                        // 100004 ints
    float*  inv     = (float*)(off + 100004);            // 100004 floats
    int*    bcnt    = (int*)(inv + 100004);              // 392*16 ints (padded)
    int*    bbase   = bcnt + 392 * PAD;                  // 392+8 ints
    int*    bcur    = bbase + 400;                       // 392*16 ints (padded)
    int*    csr_src = bcur + 392 * PAD;                  // 1600000 ints
    ushort* w1t     = (ushort*)(csr_src + 1600000);      // 128*128 bf16
    ushort* w2t     = w1t + 128 * 128;                   // 64*128 bf16
    ushort* h       = w2t + 64 * 128;                    // NN*128 bf16
    ushort* hagg    = h + (size_t)NN * DH;               // NN*128 bf16
    ushort* h2      = hagg + (size_t)NN * DH;            // NN*64 bf16
    uint2*  ebuf    = (uint2*)h2;                        // NE uint2, aliases h2 (dead until gemm2)

    // CSR build: bucket sort (A-D), emits off/inv/csr_src
    k_zero<<<25, 256, 0, stream>>>(bcnt, 392 * PAD);
    k_bhist<<<1024, 256, 0, stream>>>(dst, bcnt);
    k_bscan<<<1, 512, 0, stream>>>(bcnt, bbase, bcur);
    k_bscatter<<<(NE + 255) / 256, 256, 0, stream>>>(src, dst, bcur, ebuf);
    k_bfill<<<NBK, 256, 0, stream>>>(ebuf, bbase, off, inv, csr_src);

    // weight prep
    k_wt<<<64, 256, 0, stream>>>(W1, w1t, 128, 128);
    k_wt<<<32, 256, 0, stream>>>(W2, w2t, 128, 64);

    // layer 1: h = bf16(x @ W1) ; hagg = bf16(relu(A_hat h + b1))
    k_gemm_mfma<DH, false><<<(NN + 127) / 128, 256, 0, stream>>>(x, w1t, h);
    k_agg128<true><<<NN / 4, 256, 0, stream>>>(off, csr_src, h, inv, b1, hagg);

    // layer 2: h2 = bf16(hagg @ W2) ; out = A_hat h2 + b2  (fp32)
    k_gemm_mfma<DO, true><<<(NN + 127) / 128, 256, 0, stream>>>(hagg, w2t, h2);
    k_agg64<<<NN / 4, 256, 0, stream>>>(off, csr_src, h2, inv, b2, out);
}